// Round 3
// baseline (163.818 us; speedup 1.0000x reference)
//
#include <hip/hip_runtime.h>
#include <math.h>

#define DM    512
#define LSEQ  256
#define NB    2
#define NH    8
#define DK    64
#define SCALEF 0.125f   // 64^-0.5

// ---------------------------------------------------------------------------
// Kernel A: Q/K tropical linears + V linear + gating, selected by blockIdx.z
//   z=0: Q = maxplus(x, qW) + qb      (tropical)
//   z=1: K = maxplus(x, kW) + kb      (tropical)
//   z=2: V = x @ vW^T + vb            (plain)
//   z=3: g = sigmoid(x @ gW^T + gb)   (by==0 only)
// Tile 32x32, k-chunk 64 (16 syncs/block), 256 threads, 2x2 register tile.
// LDS stride 68 floats keeps float4 alignment; x-reads broadcast (4 unique
// rows/wave), w-reads 16 unique rows -> ~2x bank aliasing, acceptable.
// Tropical uses fmaxf(fmaxf(a,s0),s1) nests -> v_max3_f32 fusion (exact).
// ---------------------------------------------------------------------------
__global__ __launch_bounds__(256) void qkvg_kernel(
    const float* __restrict__ x,
    const float* __restrict__ qW, const float* __restrict__ qb,
    const float* __restrict__ kW, const float* __restrict__ kb,
    const float* __restrict__ vW, const float* __restrict__ vb,
    const float* __restrict__ gW, const float* __restrict__ gb,
    float* __restrict__ Qo, float* __restrict__ Ko,
    float* __restrict__ Vo, float* __restrict__ go)
{
    const int tid = threadIdx.x;
    const int op  = blockIdx.z;

    if (op == 3) {
        if (blockIdx.y != 0) return;
        const int row = blockIdx.x * 32 + (tid >> 3);
        const int h   = tid & 7;
        const float4* xr = (const float4*)(x  + row * DM);
        const float4* wr = (const float4*)(gW + h  * DM);
        float acc = 0.f;
        #pragma unroll 8
        for (int i = 0; i < DM / 4; ++i) {
            float4 a = xr[i], w = wr[i];
            acc = fmaf(a.x, w.x, acc);
            acc = fmaf(a.y, w.y, acc);
            acc = fmaf(a.z, w.z, acc);
            acc = fmaf(a.w, w.w, acc);
        }
        acc += gb[h];
        go[row * NH + h] = 1.f / (1.f + __expf(-acc));
        return;
    }

    const float* __restrict__ W;
    const float* __restrict__ bias;
    float* __restrict__ out;
    bool trop;
    if      (op == 0) { W = qW; bias = qb; out = Qo; trop = true;  }
    else if (op == 1) { W = kW; bias = kb; out = Ko; trop = true;  }
    else              { W = vW; bias = vb; out = Vo; trop = false; }

    __shared__ float Xs[32][68];
    __shared__ float Ws[32][68];

    const int row0 = blockIdx.x * 32;
    const int col0 = blockIdx.y * 32;
    const int ty = tid >> 4, tx = tid & 15;   // 16 x 16 thread grid
    const int ra = ty;                        // staging row (and +16)
    const int c4 = tx * 4;                    // staging col within k-chunk

    const float* xp0 = x + (row0 + ra) * DM + c4;
    const float* xp1 = xp0 + 16 * DM;
    const float* wp0 = W + (col0 + ra) * DM + c4;
    const float* wp1 = wp0 + 16 * DM;

    float4 xv0 = *(const float4*)xp0;
    float4 xv1 = *(const float4*)xp1;
    float4 wv0 = *(const float4*)wp0;
    float4 wv1 = *(const float4*)wp1;

    const float init = trop ? -INFINITY : 0.f;
    float a00 = init, a01 = init, a10 = init, a11 = init;

    for (int k0 = 0; k0 < DM; k0 += 64) {
        __syncthreads();                       // previous chunk consumed
        *(float4*)&Xs[ra     ][c4] = xv0;
        *(float4*)&Xs[ra + 16][c4] = xv1;
        *(float4*)&Ws[ra     ][c4] = wv0;
        *(float4*)&Ws[ra + 16][c4] = wv1;
        __syncthreads();                       // chunk visible
        if (k0 + 64 < DM) {                    // prefetch next chunk
            xv0 = *(const float4*)(xp0 + k0 + 64);
            xv1 = *(const float4*)(xp1 + k0 + 64);
            wv0 = *(const float4*)(wp0 + k0 + 64);
            wv1 = *(const float4*)(wp1 + k0 + 64);
        }
        if (trop) {
            #pragma unroll
            for (int kq = 0; kq < 16; ++kq) {
                float4 x0 = *(const float4*)&Xs[ty*2    ][kq*4];
                float4 x1 = *(const float4*)&Xs[ty*2 + 1][kq*4];
                float4 w0 = *(const float4*)&Ws[tx*2    ][kq*4];
                float4 w1 = *(const float4*)&Ws[tx*2 + 1][kq*4];
                // 4 adds + 2 max3 per accumulator (exact: max is associative)
                a00 = fmaxf(fmaxf(a00, x0.x + w0.x), x0.y + w0.y);
                a00 = fmaxf(fmaxf(a00, x0.z + w0.z), x0.w + w0.w);
                a01 = fmaxf(fmaxf(a01, x0.x + w1.x), x0.y + w1.y);
                a01 = fmaxf(fmaxf(a01, x0.z + w1.z), x0.w + w1.w);
                a10 = fmaxf(fmaxf(a10, x1.x + w0.x), x1.y + w0.y);
                a10 = fmaxf(fmaxf(a10, x1.z + w0.z), x1.w + w0.w);
                a11 = fmaxf(fmaxf(a11, x1.x + w1.x), x1.y + w1.y);
                a11 = fmaxf(fmaxf(a11, x1.z + w1.z), x1.w + w1.w);
            }
        } else {
            #pragma unroll
            for (int kq = 0; kq < 16; ++kq) {
                float4 x0 = *(const float4*)&Xs[ty*2    ][kq*4];
                float4 x1 = *(const float4*)&Xs[ty*2 + 1][kq*4];
                float4 w0 = *(const float4*)&Ws[tx*2    ][kq*4];
                float4 w1 = *(const float4*)&Ws[tx*2 + 1][kq*4];
                a00 = fmaf(x0.x, w0.x, a00); a00 = fmaf(x0.y, w0.y, a00);
                a00 = fmaf(x0.z, w0.z, a00); a00 = fmaf(x0.w, w0.w, a00);
                a01 = fmaf(x0.x, w1.x, a01); a01 = fmaf(x0.y, w1.y, a01);
                a01 = fmaf(x0.z, w1.z, a01); a01 = fmaf(x0.w, w1.w, a01);
                a10 = fmaf(x1.x, w0.x, a10); a10 = fmaf(x1.y, w0.y, a10);
                a10 = fmaf(x1.z, w0.z, a10); a10 = fmaf(x1.w, w0.w, a10);
                a11 = fmaf(x1.x, w1.x, a11); a11 = fmaf(x1.y, w1.y, a11);
                a11 = fmaf(x1.z, w1.z, a11); a11 = fmaf(x1.w, w1.w, a11);
            }
        }
    }

    const int r0 = row0 + ty * 2, c0 = col0 + tx * 2;
    const float b0 = bias[c0], b1 = bias[c0 + 1];
    *(float2*)&out[(size_t)r0      * DM + c0] = make_float2(a00 + b0, a01 + b1);
    *(float2*)&out[(size_t)(r0+1)  * DM + c0] = make_float2(a10 + b0, a11 + b1);
}

// ---------------------------------------------------------------------------
// Kernel B: attention. One block per (b,h, q-tile of 16), 512 threads
// (8 waves -> 2/SIMD occupancy). ty=q-row (16), tx=0..31.
// Score phase: thread owns k-cols {tx, tx+32} per 64-wide K tile.
// Softmax: 32-lane shfl groups. PV: thread owns d-pair {2tx, 2tx+1}.
// ---------------------------------------------------------------------------
__global__ __launch_bounds__(512) void attn_kernel(
    const float* __restrict__ Q, const float* __restrict__ K,
    const float* __restrict__ V, const float* __restrict__ g,
    const float* __restrict__ temp,
    float* __restrict__ attn_out, float* __restrict__ hout)
{
    const int tid = threadIdx.x;
    const int bh  = blockIdx.y;
    const int b   = bh >> 3, h = bh & 7;
    const int q0  = blockIdx.x * 16;
    const int ty  = tid >> 5;        // 0..15 q-row
    const int tx  = tid & 31;        // 0..31

    __shared__ float Qs[16][68];
    __shared__ float KVs[64][68];
    __shared__ float Ss[16][260];

    if (tid < 256) {   // Q tile: 16 rows x 16 float4
        const int r = tid >> 4, c = (tid & 15) * 4;
        float4 v = *(const float4*)&Q[(b * LSEQ + q0 + r) * DM + h * DK + c];
        *(float4*)&Qs[r][c] = v;
    }
    const float gq   = g[(b * LSEQ + q0 + ty) * NH + h];
    const float invt = SCALEF / temp[h];

    // ---- scores ----
    for (int kt = 0; kt < 4; ++kt) {
        __syncthreads();
        #pragma unroll
        for (int i = 0; i < 2; ++i) {
            const int f = tid + 512 * i;
            const int r = f >> 4, c = (f & 15) * 4;
            float4 v = *(const float4*)&K[(b * LSEQ + kt * 64 + r) * DM + h * DK + c];
            *(float4*)&KVs[r][c] = v;
        }
        __syncthreads();
        float d0 = 0.f, d1 = 0.f;
        float t0 = -INFINITY, t1 = -INFINITY;
        #pragma unroll
        for (int dq = 0; dq < 16; ++dq) {
            float4 q  = *(const float4*)&Qs[ty][dq * 4];
            float4 k0 = *(const float4*)&KVs[tx     ][dq * 4];
            float4 k1 = *(const float4*)&KVs[tx + 32][dq * 4];
            d0 = fmaf(q.x, k0.x, d0); d0 = fmaf(q.y, k0.y, d0);
            d0 = fmaf(q.z, k0.z, d0); d0 = fmaf(q.w, k0.w, d0);
            d1 = fmaf(q.x, k1.x, d1); d1 = fmaf(q.y, k1.y, d1);
            d1 = fmaf(q.z, k1.z, d1); d1 = fmaf(q.w, k1.w, d1);
            t0 = fmaxf(fmaxf(t0, q.x + k0.x), q.y + k0.y);
            t0 = fmaxf(fmaxf(t0, q.z + k0.z), q.w + k0.w);
            t1 = fmaxf(fmaxf(t1, q.x + k1.x), q.y + k1.y);
            t1 = fmaxf(fmaxf(t1, q.z + k1.z), q.w + k1.w);
        }
        Ss[ty][kt*64 + tx     ] = (gq * t0 + (1.f - gq) * d0) * invt;
        Ss[ty][kt*64 + tx + 32] = (gq * t1 + (1.f - gq) * d1) * invt;
    }
    __syncthreads();

    // ---- softmax: row ty, 32 lanes (tx) x 8 elems each ----
    {
        float m = -INFINITY;
        #pragma unroll
        for (int j = 0; j < 8; ++j) m = fmaxf(m, Ss[ty][tx + 32 * j]);
        #pragma unroll
        for (int o = 16; o; o >>= 1) m = fmaxf(m, __shfl_xor(m, o));
        float s = 0.f;
        #pragma unroll
        for (int j = 0; j < 8; ++j) {
            const float e = __expf(Ss[ty][tx + 32 * j] - m);
            Ss[ty][tx + 32 * j] = e;
            s += e;
        }
        #pragma unroll
        for (int o = 16; o; o >>= 1) s += __shfl_xor(s, o);
        const float rs = 1.f / s;
        #pragma unroll
        for (int j = 0; j < 8; ++j) Ss[ty][tx + 32 * j] *= rs;
    }
    __syncthreads();

    // ---- write attn tile (coalesced float4) ----
    {
        float* dst = attn_out + (size_t)(bh * LSEQ + q0) * LSEQ;
        #pragma unroll
        for (int i = 0; i < 2; ++i) {
            const int fi  = i * 2048 + tid * 4;
            const int row = fi >> 8, col = fi & 255;
            float4 v = *(const float4*)&Ss[row][col];
            *(float4*)&dst[fi] = v;
        }
    }

    // ---- PV: thread owns q-row ty, d-pair {2tx, 2tx+1} ----
    float acc0 = 0.f, acc1 = 0.f;
    for (int kt = 0; kt < 4; ++kt) {
        __syncthreads();
        #pragma unroll
        for (int i = 0; i < 2; ++i) {
            const int f = tid + 512 * i;
            const int r = f >> 4, c = (f & 15) * 4;
            float4 v = *(const float4*)&V[(b * LSEQ + kt * 64 + r) * DM + h * DK + c];
            *(float4*)&KVs[r][c] = v;
        }
        __syncthreads();
        #pragma unroll
        for (int kq = 0; kq < 16; ++kq) {
            float4 a = *(const float4*)&Ss[ty][kt * 64 + kq * 4];
            const int k = kq * 4;
            float2 v0 = *(const float2*)&KVs[k    ][tx * 2];
            float2 v1 = *(const float2*)&KVs[k + 1][tx * 2];
            float2 v2 = *(const float2*)&KVs[k + 2][tx * 2];
            float2 v3 = *(const float2*)&KVs[k + 3][tx * 2];
            acc0 = fmaf(a.x, v0.x, acc0); acc1 = fmaf(a.x, v0.y, acc1);
            acc0 = fmaf(a.y, v1.x, acc0); acc1 = fmaf(a.y, v1.y, acc1);
            acc0 = fmaf(a.z, v2.x, acc0); acc1 = fmaf(a.z, v2.y, acc1);
            acc0 = fmaf(a.w, v3.x, acc0); acc1 = fmaf(a.w, v3.y, acc1);
        }
    }
    *(float2*)&hout[(size_t)(bh * LSEQ + q0 + ty) * DK + tx * 2] =
        make_float2(acc0, acc1);
}

// ---------------------------------------------------------------------------
// Kernel C: final projection out = merge_heads(hout) @ oW^T + ob
// hout is (B,H,L,dk); 64-wide k-chunks map to exactly one head.
// Same structure as kernel A (k-chunk 64, 2x2 tile).
// ---------------------------------------------------------------------------
__global__ __launch_bounds__(256) void oproj_kernel(
    const float* __restrict__ hout,
    const float* __restrict__ oW, const float* __restrict__ ob,
    float* __restrict__ out)
{
    __shared__ float Xs[32][68];
    __shared__ float Ws[32][68];
    const int tid = threadIdx.x;
    const int ty = tid >> 4, tx = tid & 15;
    const int row0 = blockIdx.x * 32;
    const int col0 = blockIdx.y * 32;
    const int ra = ty;
    const int c4 = tx * 4;

    const int grow = row0 + ra;            // block never straddles batch bound
    const int bb = grow >> 8, ll = grow & 255;

    const float* wp0 = oW + (col0 + ra) * DM + c4;
    const float* wp1 = wp0 + 16 * DM;

    float a00 = 0.f, a01 = 0.f, a10 = 0.f, a11 = 0.f;

    // prefetch chunk 0 (head 0)
    float4 xv0 = *(const float4*)&hout[((bb * NH + 0) * LSEQ + ll     ) * DK + c4];
    float4 xv1 = *(const float4*)&hout[((bb * NH + 0) * LSEQ + ll + 16) * DK + c4];
    float4 wv0 = *(const float4*)wp0;
    float4 wv1 = *(const float4*)wp1;

    for (int k0 = 0; k0 < DM; k0 += 64) {
        __syncthreads();
        *(float4*)&Xs[ra     ][c4] = xv0;
        *(float4*)&Xs[ra + 16][c4] = xv1;
        *(float4*)&Ws[ra     ][c4] = wv0;
        *(float4*)&Ws[ra + 16][c4] = wv1;
        __syncthreads();
        if (k0 + 64 < DM) {
            const int hh = (k0 >> 6) + 1;
            xv0 = *(const float4*)&hout[((bb * NH + hh) * LSEQ + ll     ) * DK + c4];
            xv1 = *(const float4*)&hout[((bb * NH + hh) * LSEQ + ll + 16) * DK + c4];
            wv0 = *(const float4*)(wp0 + k0 + 64);
            wv1 = *(const float4*)(wp1 + k0 + 64);
        }
        #pragma unroll
        for (int kq = 0; kq < 16; ++kq) {
            float4 x0 = *(const float4*)&Xs[ty*2    ][kq*4];
            float4 x1 = *(const float4*)&Xs[ty*2 + 1][kq*4];
            float4 w0 = *(const float4*)&Ws[tx*2    ][kq*4];
            float4 w1 = *(const float4*)&Ws[tx*2 + 1][kq*4];
            a00 = fmaf(x0.x, w0.x, a00); a00 = fmaf(x0.y, w0.y, a00);
            a00 = fmaf(x0.z, w0.z, a00); a00 = fmaf(x0.w, w0.w, a00);
            a01 = fmaf(x0.x, w1.x, a01); a01 = fmaf(x0.y, w1.y, a01);
            a01 = fmaf(x0.z, w1.z, a01); a01 = fmaf(x0.w, w1.w, a01);
            a10 = fmaf(x1.x, w0.x, a10); a10 = fmaf(x1.y, w0.y, a10);
            a10 = fmaf(x1.z, w0.z, a10); a10 = fmaf(x1.w, w0.w, a10);
            a11 = fmaf(x1.x, w1.x, a11); a11 = fmaf(x1.y, w1.y, a11);
            a11 = fmaf(x1.z, w1.z, a11); a11 = fmaf(x1.w, w1.w, a11);
        }
    }

    const int r0 = row0 + ty * 2, c0 = col0 + tx * 2;
    const float b0 = ob[c0], b1 = ob[c0 + 1];
    *(float2*)&out[(size_t)r0     * DM + c0] = make_float2(a00 + b0, a01 + b1);
    *(float2*)&out[(size_t)(r0+1) * DM + c0] = make_float2(a10 + b0, a11 + b1);
}

extern "C" void kernel_launch(void* const* d_in, const int* in_sizes, int n_in,
                              void* d_out, int out_size, void* d_ws, size_t ws_size,
                              hipStream_t stream)
{
    const float* x    = (const float*)d_in[0];
    const float* qW   = (const float*)d_in[1];
    const float* qb   = (const float*)d_in[2];
    const float* kW   = (const float*)d_in[3];
    const float* kb   = (const float*)d_in[4];
    const float* vW   = (const float*)d_in[5];
    const float* vb   = (const float*)d_in[6];
    const float* oW   = (const float*)d_in[7];
    const float* ob   = (const float*)d_in[8];
    const float* gW   = (const float*)d_in[9];
    const float* gb   = (const float*)d_in[10];
    const float* temp = (const float*)d_in[11];

    float* out      = (float*)d_out;                 // (B,L,512)
    float* attn_out = out + NB * LSEQ * DM;          // (B,H,L,L)

    float* ws   = (float*)d_ws;
    float* Qo   = ws;                                // (B,L,512)
    float* Ko   = Qo + NB * LSEQ * DM;               // (B,L,512)
    float* Vo   = Ko + NB * LSEQ * DM;               // (B,L,512)
    float* go   = Vo + NB * LSEQ * DM;               // (B,L,H)
    float* hout = go + NB * LSEQ * NH;               // (B,H,L,dk)

    qkvg_kernel<<<dim3(16, 16, 4), 256, 0, stream>>>(
        x, qW, qb, kW, kb, vW, vb, gW, gb, Qo, Ko, Vo, go);
    attn_kernel<<<dim3(16, 16), 512, 0, stream>>>(
        Qo, Ko, Vo, go, temp, attn_out, hout);
    oproj_kernel<<<dim3(16, 16), 256, 0, stream>>>(
        hout, oW, ob, out);
}

// Round 4
// 154.008 us; speedup vs baseline: 1.0637x; 1.0637x over previous
//
#include <hip/hip_runtime.h>
#include <math.h>

#define DM    512
#define LSEQ  256
#define NB    2
#define NH    8
#define DK    64
#define SCALEF 0.125f   // 64^-0.5
#define KC    64        // k-chunk for GEMM kernels

// ---------------------------------------------------------------------------
// Kernel A: fused QKV (cols 0..1535 of [qW;kW;vW]) + gating.
// 1D grid, 208 blocks:
//   bx in [0,192): GEMM block. ct = bx%24 selects col-tile; op = ct/8
//     (0: Q tropical, 1: K tropical, 2: V fma). 64x64 tile, 256 thr, 4x4/thread.
//   bx in [192,208): gating, 32 rows each.
// LDS is K-MAJOR: Xs[kk][row], Ws[kk][col], stride 68 floats.
//   reads:  x = b128 @ [kk][4ty] (4 uniq, bcast16, free)
//           w = b128 @ [kk][4tx] (bank (4kk+4tx)%32, 2-way, free)
//   writes: sr=tid&63 (sq wave-uniform) -> bank (16i+4c+sr)%32, 2-way, free
// Tropical pairs kk so fmaxf(fmaxf(a,s0),s1) -> v_max3_f32 (exact).
// ---------------------------------------------------------------------------
__global__ __launch_bounds__(256) void qkvg_kernel(
    const float* __restrict__ x,
    const float* __restrict__ qW, const float* __restrict__ qb,
    const float* __restrict__ kW, const float* __restrict__ kb,
    const float* __restrict__ vW, const float* __restrict__ vb,
    const float* __restrict__ gW, const float* __restrict__ gb,
    float* __restrict__ Qo, float* __restrict__ Ko,
    float* __restrict__ Vo, float* __restrict__ go)
{
    const int tid = threadIdx.x;
    const int bx  = blockIdx.x;

    if (bx >= 192) {  // ---- gating ----
        const int gx  = bx - 192;
        const int row = gx * 32 + (tid >> 3);
        const int h   = tid & 7;
        const float4* xr = (const float4*)(x  + row * DM);
        const float4* wr = (const float4*)(gW + h  * DM);
        float acc = 0.f;
        #pragma unroll 8
        for (int i = 0; i < DM / 4; ++i) {
            float4 a = xr[i], w = wr[i];
            acc = fmaf(a.x, w.x, acc);
            acc = fmaf(a.y, w.y, acc);
            acc = fmaf(a.z, w.z, acc);
            acc = fmaf(a.w, w.w, acc);
        }
        acc += gb[h];
        go[row * NH + h] = 1.f / (1.f + __expf(-acc));
        return;
    }

    const int rt = bx / 24;          // 0..7 row tile
    const int ct = bx % 24;          // 0..23 col tile
    const int op = ct >> 3;          // 0 Q, 1 K, 2 V
    const int row0  = rt * 64;
    const int col0m = (ct & 7) * 64; // col within the selected matrix

    const float* __restrict__ W;
    const float* __restrict__ bias;
    float* __restrict__ out;
    bool trop;
    if      (op == 0) { W = qW; bias = qb; out = Qo; trop = true;  }
    else if (op == 1) { W = kW; bias = kb; out = Ko; trop = true;  }
    else              { W = vW; bias = vb; out = Vo; trop = false; }

    __shared__ float Xs[KC][68];
    __shared__ float Ws[KC][68];

    const int ty = tid >> 4, tx = tid & 15;
    const int sr = tid & 63;         // staging row (x-row / w-col), 0..63
    const int sq = tid >> 6;         // wave id 0..3 -> k-window sq*16

    const float* xp = x + (row0  + sr) * DM + sq * 16;
    const float* wp = W + (col0m + sr) * DM + sq * 16;

    float4 xg[4], wg[4];
    #pragma unroll
    for (int i = 0; i < 4; ++i) {
        xg[i] = *(const float4*)(xp + i * 4);
        wg[i] = *(const float4*)(wp + i * 4);
    }

    const float init = trop ? -INFINITY : 0.f;
    float acc[4][4];
    #pragma unroll
    for (int i = 0; i < 4; ++i)
        #pragma unroll
        for (int j = 0; j < 4; ++j) acc[i][j] = init;

    for (int k0 = 0; k0 < DM; k0 += KC) {
        __syncthreads();               // previous chunk consumed
        #pragma unroll
        for (int i = 0; i < 4; ++i) {  // transpose-store to k-major
            const int kk = sq * 16 + i * 4;
            Xs[kk + 0][sr] = xg[i].x;  Xs[kk + 1][sr] = xg[i].y;
            Xs[kk + 2][sr] = xg[i].z;  Xs[kk + 3][sr] = xg[i].w;
            Ws[kk + 0][sr] = wg[i].x;  Ws[kk + 1][sr] = wg[i].y;
            Ws[kk + 2][sr] = wg[i].z;  Ws[kk + 3][sr] = wg[i].w;
        }
        __syncthreads();               // chunk visible
        if (k0 + KC < DM) {            // prefetch next chunk
            #pragma unroll
            for (int i = 0; i < 4; ++i) {
                xg[i] = *(const float4*)(xp + k0 + KC + i * 4);
                wg[i] = *(const float4*)(wp + k0 + KC + i * 4);
            }
        }
        if (trop) {
            #pragma unroll 4
            for (int kp = 0; kp < KC / 2; ++kp) {
                const int kk = kp * 2;
                float4 x0 = *(const float4*)&Xs[kk    ][ty * 4];
                float4 x1 = *(const float4*)&Xs[kk + 1][ty * 4];
                float4 w0 = *(const float4*)&Ws[kk    ][tx * 4];
                float4 w1 = *(const float4*)&Ws[kk + 1][tx * 4];
                const float xa0[4] = {x0.x, x0.y, x0.z, x0.w};
                const float xa1[4] = {x1.x, x1.y, x1.z, x1.w};
                const float wa0[4] = {w0.x, w0.y, w0.z, w0.w};
                const float wa1[4] = {w1.x, w1.y, w1.z, w1.w};
                #pragma unroll
                for (int i = 0; i < 4; ++i)
                    #pragma unroll
                    for (int j = 0; j < 4; ++j)
                        acc[i][j] = fmaxf(fmaxf(acc[i][j], xa0[i] + wa0[j]),
                                          xa1[i] + wa1[j]);
            }
        } else {
            #pragma unroll 4
            for (int kp = 0; kp < KC / 2; ++kp) {
                const int kk = kp * 2;
                float4 x0 = *(const float4*)&Xs[kk    ][ty * 4];
                float4 x1 = *(const float4*)&Xs[kk + 1][ty * 4];
                float4 w0 = *(const float4*)&Ws[kk    ][tx * 4];
                float4 w1 = *(const float4*)&Ws[kk + 1][tx * 4];
                const float xa0[4] = {x0.x, x0.y, x0.z, x0.w};
                const float xa1[4] = {x1.x, x1.y, x1.z, x1.w};
                const float wa0[4] = {w0.x, w0.y, w0.z, w0.w};
                const float wa1[4] = {w1.x, w1.y, w1.z, w1.w};
                #pragma unroll
                for (int i = 0; i < 4; ++i)
                    #pragma unroll
                    for (int j = 0; j < 4; ++j) {
                        acc[i][j] = fmaf(xa0[i], wa0[j], acc[i][j]);
                        acc[i][j] = fmaf(xa1[i], wa1[j], acc[i][j]);
                    }
            }
        }
    }

    const float4 bv = *(const float4*)&bias[col0m + tx * 4];
    #pragma unroll
    for (int i = 0; i < 4; ++i) {
        const int r = row0 + ty * 4 + i;
        float4 o = make_float4(acc[i][0] + bv.x, acc[i][1] + bv.y,
                               acc[i][2] + bv.z, acc[i][3] + bv.w);
        *(float4*)&out[(size_t)r * DM + col0m + tx * 4] = o;
    }
}

// ---------------------------------------------------------------------------
// Kernel B: attention. Block = (q-tile 16, bh). 256 threads (ty=q-row, tx).
// Q row in REGISTERS (statically indexed, full unroll). K staged k-major
// (Kd[d][kcol], stride 68, conflict-free). V staged row-major direct.
// Scores: thread owns 4 kcols; softmax in 16-lane shfl groups; PV: thread
// owns 4 d-cols. hout written merged [b][l][h*64+d].
// ---------------------------------------------------------------------------
__global__ __launch_bounds__(256) void attn_kernel(
    const float* __restrict__ Q, const float* __restrict__ K,
    const float* __restrict__ V, const float* __restrict__ g,
    const float* __restrict__ temp,
    float* __restrict__ attn_out, float* __restrict__ hout)
{
    const int tid = threadIdx.x;
    const int bh  = blockIdx.y;
    const int b   = bh >> 3, h = bh & 7;
    const int q0  = blockIdx.x * 16;
    const int ty  = tid >> 4, tx = tid & 15;

    __shared__ float Kd[64][68];   // k-major K tile: [d][kcol]
    __shared__ float Vs[64][68];   // row-major V tile: [k][d]
    __shared__ float Ss[16][260];  // scores/attn

    // Q row -> 16 float4 registers (static index after unroll)
    const float* qrow = Q + (size_t)(b * LSEQ + q0 + ty) * DM + h * DK;
    float4 qreg[16];
    #pragma unroll
    for (int i = 0; i < 16; ++i) qreg[i] = *(const float4*)(qrow + i * 4);

    const float gq   = g[(b * LSEQ + q0 + ty) * NH + h];
    const float invt = SCALEF / temp[h];

    const int sr = tid & 63;   // staging row, 0..63
    const int sq = tid >> 6;   // wave id 0..3

    // ---- scores ----
    for (int kt = 0; kt < 4; ++kt) {
        __syncthreads();
        {   // stage K transposed: Kd[d][kcol]
            const float* kp = K + (size_t)(b * LSEQ + kt * 64 + sr) * DM
                              + h * DK + sq * 16;
            #pragma unroll
            for (int i = 0; i < 4; ++i) {
                float4 v = *(const float4*)(kp + i * 4);
                const int d = sq * 16 + i * 4;
                Kd[d + 0][sr] = v.x;  Kd[d + 1][sr] = v.y;
                Kd[d + 2][sr] = v.z;  Kd[d + 3][sr] = v.w;
            }
        }
        __syncthreads();
        float d0 = 0.f, d1 = 0.f, d2 = 0.f, d3 = 0.f;
        float t0 = -INFINITY, t1 = -INFINITY, t2 = -INFINITY, t3 = -INFINITY;
        #pragma unroll
        for (int k4 = 0; k4 < 16; ++k4) {
            const float4 q4 = qreg[k4];
            float4 ka = *(const float4*)&Kd[k4 * 4 + 0][tx * 4];
            float4 kb = *(const float4*)&Kd[k4 * 4 + 1][tx * 4];
            float4 kc = *(const float4*)&Kd[k4 * 4 + 2][tx * 4];
            float4 kd = *(const float4*)&Kd[k4 * 4 + 3][tx * 4];
            d0 = fmaf(q4.x, ka.x, d0); d0 = fmaf(q4.y, kb.x, d0);
            d0 = fmaf(q4.z, kc.x, d0); d0 = fmaf(q4.w, kd.x, d0);
            d1 = fmaf(q4.x, ka.y, d1); d1 = fmaf(q4.y, kb.y, d1);
            d1 = fmaf(q4.z, kc.y, d1); d1 = fmaf(q4.w, kd.y, d1);
            d2 = fmaf(q4.x, ka.z, d2); d2 = fmaf(q4.y, kb.z, d2);
            d2 = fmaf(q4.z, kc.z, d2); d2 = fmaf(q4.w, kd.z, d2);
            d3 = fmaf(q4.x, ka.w, d3); d3 = fmaf(q4.y, kb.w, d3);
            d3 = fmaf(q4.z, kc.w, d3); d3 = fmaf(q4.w, kd.w, d3);
            t0 = fmaxf(fmaxf(t0, q4.x + ka.x), q4.y + kb.x);
            t0 = fmaxf(fmaxf(t0, q4.z + kc.x), q4.w + kd.x);
            t1 = fmaxf(fmaxf(t1, q4.x + ka.y), q4.y + kb.y);
            t1 = fmaxf(fmaxf(t1, q4.z + kc.y), q4.w + kd.y);
            t2 = fmaxf(fmaxf(t2, q4.x + ka.z), q4.y + kb.z);
            t2 = fmaxf(fmaxf(t2, q4.z + kc.z), q4.w + kd.z);
            t3 = fmaxf(fmaxf(t3, q4.x + ka.w), q4.y + kb.w);
            t3 = fmaxf(fmaxf(t3, q4.z + kc.w), q4.w + kd.w);
        }
        const float gi = 1.f - gq;
        *(float4*)&Ss[ty][kt * 64 + tx * 4] = make_float4(
            (gq * t0 + gi * d0) * invt, (gq * t1 + gi * d1) * invt,
            (gq * t2 + gi * d2) * invt, (gq * t3 + gi * d3) * invt);
    }
    __syncthreads();

    // ---- softmax: row ty, 16 lanes (tx) x 16 elems ----
    {
        float m = -INFINITY;
        #pragma unroll 4
        for (int j = 0; j < 16; ++j) m = fmaxf(m, Ss[ty][tx + 16 * j]);
        #pragma unroll
        for (int o = 8; o; o >>= 1) m = fmaxf(m, __shfl_xor(m, o));
        float s = 0.f;
        #pragma unroll 4
        for (int j = 0; j < 16; ++j) {
            const float e = __expf(Ss[ty][tx + 16 * j] - m);
            Ss[ty][tx + 16 * j] = e;
            s += e;
        }
        #pragma unroll
        for (int o = 8; o; o >>= 1) s += __shfl_xor(s, o);
        const float rs = 1.f / s;
        #pragma unroll 4
        for (int j = 0; j < 16; ++j) Ss[ty][tx + 16 * j] *= rs;
    }

    // ---- write attn tile (own row, coalesced float4 per 16-lane group) ----
    {
        float* dst = attn_out + (size_t)(bh * LSEQ + q0 + ty) * LSEQ;
        #pragma unroll
        for (int j = 0; j < 4; ++j)
            *(float4*)&dst[j * 64 + tx * 4] =
                *(const float4*)&Ss[ty][j * 64 + tx * 4];
    }

    // ---- PV: thread owns q-row ty, d-cols 4tx..4tx+3 ----
    float o0 = 0.f, o1 = 0.f, o2 = 0.f, o3 = 0.f;
    const int vr = tid & 63;   // V row copied by this thread
    const int vc = tid >> 6;   // 16-float window
    for (int kt = 0; kt < 4; ++kt) {
        __syncthreads();
        {   // stage V direct (row-major)
            const float* vp = V + (size_t)(b * LSEQ + kt * 64 + vr) * DM
                              + h * DK + vc * 16;
            #pragma unroll
            for (int i = 0; i < 4; ++i)
                *(float4*)&Vs[vr][vc * 16 + i * 4] = *(const float4*)(vp + i * 4);
        }
        __syncthreads();
        #pragma unroll 8
        for (int k2 = 0; k2 < 32; ++k2) {
            float2 a2 = *(const float2*)&Ss[ty][kt * 64 + k2 * 2];
            float4 v0 = *(const float4*)&Vs[k2 * 2    ][tx * 4];
            float4 v1 = *(const float4*)&Vs[k2 * 2 + 1][tx * 4];
            o0 = fmaf(a2.x, v0.x, o0); o0 = fmaf(a2.y, v1.x, o0);
            o1 = fmaf(a2.x, v0.y, o1); o1 = fmaf(a2.y, v1.y, o1);
            o2 = fmaf(a2.x, v0.z, o2); o2 = fmaf(a2.y, v1.z, o2);
            o3 = fmaf(a2.x, v0.w, o3); o3 = fmaf(a2.y, v1.w, o3);
        }
    }
    *(float4*)&hout[(size_t)(b * LSEQ + q0 + ty) * DM + h * DK + tx * 4] =
        make_float4(o0, o1, o2, o3);
}

// ---------------------------------------------------------------------------
// Kernel C: out = hout @ oW^T + ob. hout is merged [b][l][512] (row-major).
// 32x32 tiles, 256 blocks, T=2x2, k-major LDS stride 36 (b64 reads free).
// ---------------------------------------------------------------------------
__global__ __launch_bounds__(256) void oproj_kernel(
    const float* __restrict__ hout,
    const float* __restrict__ oW, const float* __restrict__ ob,
    float* __restrict__ out)
{
    const int tid = threadIdx.x;
    const int bx  = blockIdx.x;
    const int row0 = (bx >> 4) * 32;
    const int col0 = (bx & 15) * 32;

    __shared__ float Xs[KC][36];
    __shared__ float Ws[KC][36];

    const int ty = tid >> 4, tx = tid & 15;
    const int sr = tid & 31;   // staged row/col 0..31
    const int sq = tid >> 5;   // k-window sq*8, 0..7

    const float* xp = hout + (size_t)(row0 + sr) * DM + sq * 8;
    const float* wp = oW   + (size_t)(col0 + sr) * DM + sq * 8;

    float4 xg[2], wg[2];
    #pragma unroll
    for (int i = 0; i < 2; ++i) {
        xg[i] = *(const float4*)(xp + i * 4);
        wg[i] = *(const float4*)(wp + i * 4);
    }

    float a00 = 0.f, a01 = 0.f, a10 = 0.f, a11 = 0.f;

    for (int k0 = 0; k0 < DM; k0 += KC) {
        __syncthreads();
        #pragma unroll
        for (int i = 0; i < 2; ++i) {
            const int kk = sq * 8 + i * 4;
            Xs[kk + 0][sr] = xg[i].x;  Xs[kk + 1][sr] = xg[i].y;
            Xs[kk + 2][sr] = xg[i].z;  Xs[kk + 3][sr] = xg[i].w;
            Ws[kk + 0][sr] = wg[i].x;  Ws[kk + 1][sr] = wg[i].y;
            Ws[kk + 2][sr] = wg[i].z;  Ws[kk + 3][sr] = wg[i].w;
        }
        __syncthreads();
        if (k0 + KC < DM) {
            #pragma unroll
            for (int i = 0; i < 2; ++i) {
                xg[i] = *(const float4*)(xp + k0 + KC + i * 4);
                wg[i] = *(const float4*)(wp + k0 + KC + i * 4);
            }
        }
        #pragma unroll 8
        for (int kk = 0; kk < KC; ++kk) {
            float2 xv = *(const float2*)&Xs[kk][ty * 2];
            float2 wv = *(const float2*)&Ws[kk][tx * 2];
            a00 = fmaf(xv.x, wv.x, a00);
            a01 = fmaf(xv.x, wv.y, a01);
            a10 = fmaf(xv.y, wv.x, a10);
            a11 = fmaf(xv.y, wv.y, a11);
        }
    }

    const int r0 = row0 + ty * 2, c0 = col0 + tx * 2;
    const float b0 = ob[c0], b1 = ob[c0 + 1];
    *(float2*)&out[(size_t)r0       * DM + c0] = make_float2(a00 + b0, a01 + b1);
    *(float2*)&out[(size_t)(r0 + 1) * DM + c0] = make_float2(a10 + b0, a11 + b1);
}

extern "C" void kernel_launch(void* const* d_in, const int* in_sizes, int n_in,
                              void* d_out, int out_size, void* d_ws, size_t ws_size,
                              hipStream_t stream)
{
    const float* x    = (const float*)d_in[0];
    const float* qW   = (const float*)d_in[1];
    const float* qb   = (const float*)d_in[2];
    const float* kW   = (const float*)d_in[3];
    const float* kb   = (const float*)d_in[4];
    const float* vW   = (const float*)d_in[5];
    const float* vb   = (const float*)d_in[6];
    const float* oW   = (const float*)d_in[7];
    const float* ob   = (const float*)d_in[8];
    const float* gW   = (const float*)d_in[9];
    const float* gb   = (const float*)d_in[10];
    const float* temp = (const float*)d_in[11];

    float* out      = (float*)d_out;                 // (B,L,512)
    float* attn_out = out + NB * LSEQ * DM;          // (B,H,L,L)

    float* ws   = (float*)d_ws;
    float* Qo   = ws;                                // (B,L,512)
    float* Ko   = Qo + NB * LSEQ * DM;               // (B,L,512)
    float* Vo   = Ko + NB * LSEQ * DM;               // (B,L,512)
    float* go   = Vo + NB * LSEQ * DM;               // (B,L,H)
    float* hout = go + NB * LSEQ * NH;               // (B,L,512) merged

    qkvg_kernel<<<dim3(208), 256, 0, stream>>>(
        x, qW, qb, kW, kb, vW, vb, gW, gb, Qo, Ko, Vo, go);
    attn_kernel<<<dim3(16, 16), 256, 0, stream>>>(
        Qo, Ko, Vo, go, temp, attn_out, hout);
    oproj_kernel<<<dim3(256), 256, 0, stream>>>(
        hout, oW, ob, out);
}

// Round 6
// 141.631 us; speedup vs baseline: 1.1567x; 1.0874x over previous
//
#include <hip/hip_runtime.h>
#include <math.h>

#define DM    512
#define LSEQ  256
#define NB    2
#define NH    8
#define DK    64
#define SCALEF 0.125f   // 64^-0.5
#define KC    64        // k-chunk for GEMM kernels

// ---------------------------------------------------------------------------
// Kernel A: fused QKV GEMM, split-k=4, + gating.
// Grid 784 blocks:
//   bx < 768: GEMM. ks = bx&3 (k-split), t = bx>>2: rt = t/24 (row tile),
//     ct = t%24 -> op = ct>>3 (0 Q trop, 1 K trop, 2 V fma), col tile ct&7.
//     64x64 tile, 256 thr, 4x4/thread, k-range = 128 (2 chunks of 64).
//     Writes partial (no bias) to P1[ks][512][1536].
//   bx >= 768: gating (full k), 32 rows per block.
// LDS k-major, stride 68; staging/read banks verified 2-way max (free).
// ---------------------------------------------------------------------------
__global__ __launch_bounds__(256) void qkvg_kernel(
    const float* __restrict__ x,
    const float* __restrict__ qW, const float* __restrict__ kW,
    const float* __restrict__ vW,
    const float* __restrict__ gW, const float* __restrict__ gb,
    float* __restrict__ P1, float* __restrict__ go)
{
    const int tid = threadIdx.x;
    const int bx  = blockIdx.x;

    if (bx >= 768) {  // ---- gating ----
        const int gx  = bx - 768;
        const int row = gx * 32 + (tid >> 3);
        const int h   = tid & 7;
        const float4* xr = (const float4*)(x  + row * DM);
        const float4* wr = (const float4*)(gW + h  * DM);
        float acc = 0.f;
        #pragma unroll 8
        for (int i = 0; i < DM / 4; ++i) {
            float4 a = xr[i], w = wr[i];
            acc = fmaf(a.x, w.x, acc);
            acc = fmaf(a.y, w.y, acc);
            acc = fmaf(a.z, w.z, acc);
            acc = fmaf(a.w, w.w, acc);
        }
        acc += gb[h];
        go[row * NH + h] = 1.f / (1.f + __expf(-acc));
        return;
    }

    const int ks = bx & 3;           // k-split 0..3
    const int t  = bx >> 2;          // 0..191
    const int rt = t / 24;           // 0..7 row tile
    const int ct = t % 24;           // 0..23 col tile
    const int op = ct >> 3;          // 0 Q, 1 K, 2 V
    const int row0  = rt * 64;
    const int col0m = (ct & 7) * 64;
    const int kbase = ks * 128;

    const float* __restrict__ W = (op == 0) ? qW : (op == 1) ? kW : vW;
    const bool trop = (op < 2);

    __shared__ float Xs[KC][68];
    __shared__ float Ws[KC][68];

    const int ty = tid >> 4, tx = tid & 15;
    const int sr = tid & 63;         // staging row (x-row / w-col)
    const int sq = tid >> 6;         // wave id 0..3 -> k-window sq*16

    const float* xp = x + (row0  + sr) * DM + kbase + sq * 16;
    const float* wp = W + (col0m + sr) * DM + kbase + sq * 16;

    float4 xg[4], wg[4];
    #pragma unroll
    for (int i = 0; i < 4; ++i) {
        xg[i] = *(const float4*)(xp + i * 4);
        wg[i] = *(const float4*)(wp + i * 4);
    }

    const float init = trop ? -INFINITY : 0.f;
    float acc[4][4];
    #pragma unroll
    for (int i = 0; i < 4; ++i)
        #pragma unroll
        for (int j = 0; j < 4; ++j) acc[i][j] = init;

    #pragma unroll
    for (int k0 = 0; k0 < 128; k0 += KC) {
        __syncthreads();
        #pragma unroll
        for (int i = 0; i < 4; ++i) {  // transpose-store to k-major
            const int kk = sq * 16 + i * 4;
            Xs[kk + 0][sr] = xg[i].x;  Xs[kk + 1][sr] = xg[i].y;
            Xs[kk + 2][sr] = xg[i].z;  Xs[kk + 3][sr] = xg[i].w;
            Ws[kk + 0][sr] = wg[i].x;  Ws[kk + 1][sr] = wg[i].y;
            Ws[kk + 2][sr] = wg[i].z;  Ws[kk + 3][sr] = wg[i].w;
        }
        __syncthreads();
        if (k0 + KC < 128) {
            #pragma unroll
            for (int i = 0; i < 4; ++i) {
                xg[i] = *(const float4*)(xp + KC + i * 4);
                wg[i] = *(const float4*)(wp + KC + i * 4);
            }
        }
        if (trop) {
            #pragma unroll 4
            for (int kp = 0; kp < KC / 2; ++kp) {
                const int kk = kp * 2;
                float4 x0 = *(const float4*)&Xs[kk    ][ty * 4];
                float4 x1 = *(const float4*)&Xs[kk + 1][ty * 4];
                float4 w0 = *(const float4*)&Ws[kk    ][tx * 4];
                float4 w1 = *(const float4*)&Ws[kk + 1][tx * 4];
                const float xa0[4] = {x0.x, x0.y, x0.z, x0.w};
                const float xa1[4] = {x1.x, x1.y, x1.z, x1.w};
                const float wa0[4] = {w0.x, w0.y, w0.z, w0.w};
                const float wa1[4] = {w1.x, w1.y, w1.z, w1.w};
                #pragma unroll
                for (int i = 0; i < 4; ++i)
                    #pragma unroll
                    for (int j = 0; j < 4; ++j)
                        acc[i][j] = fmaxf(fmaxf(acc[i][j], xa0[i] + wa0[j]),
                                          xa1[i] + wa1[j]);
            }
        } else {
            #pragma unroll 4
            for (int kp = 0; kp < KC / 2; ++kp) {
                const int kk = kp * 2;
                float4 x0 = *(const float4*)&Xs[kk    ][ty * 4];
                float4 x1 = *(const float4*)&Xs[kk + 1][ty * 4];
                float4 w0 = *(const float4*)&Ws[kk    ][tx * 4];
                float4 w1 = *(const float4*)&Ws[kk + 1][tx * 4];
                const float xa0[4] = {x0.x, x0.y, x0.z, x0.w};
                const float xa1[4] = {x1.x, x1.y, x1.z, x1.w};
                const float wa0[4] = {w0.x, w0.y, w0.z, w0.w};
                const float wa1[4] = {w1.x, w1.y, w1.z, w1.w};
                #pragma unroll
                for (int i = 0; i < 4; ++i)
                    #pragma unroll
                    for (int j = 0; j < 4; ++j) {
                        acc[i][j] = fmaf(xa0[i], wa0[j], acc[i][j]);
                        acc[i][j] = fmaf(xa1[i], wa1[j], acc[i][j]);
                    }
            }
        }
    }

    const int gcol = op * 512 + col0m + tx * 4;
    #pragma unroll
    for (int i = 0; i < 4; ++i) {
        const int r = row0 + ty * 4 + i;
        *(float4*)&P1[((size_t)ks * 512 + r) * 1536 + gcol] =
            make_float4(acc[i][0], acc[i][1], acc[i][2], acc[i][3]);
    }
}

// ---------------------------------------------------------------------------
// Reduce 1: fold 4 k-split partials. col<512 -> Q (max), <1024 -> K (max),
// else V (add). Adds bias, writes separated Qo/Ko/Vo.
// 768 blocks x 256 thr, one float4 per thread.
// ---------------------------------------------------------------------------
__global__ __launch_bounds__(256) void qkv_reduce_kernel(
    const float* __restrict__ P1,
    const float* __restrict__ qb, const float* __restrict__ kb,
    const float* __restrict__ vb,
    float* __restrict__ Qo, float* __restrict__ Ko, float* __restrict__ Vo)
{
    const int e   = blockIdx.x * 256 + threadIdx.x;  // float4 index
    const int row = e / 384;
    const int col = (e % 384) * 4;
    const size_t base = (size_t)row * 1536 + col;

    float4 p0 = *(const float4*)&P1[base];
    float4 p1 = *(const float4*)&P1[base +  786432];
    float4 p2 = *(const float4*)&P1[base + 1572864];
    float4 p3 = *(const float4*)&P1[base + 2359296];

    if (col < 1024) {  // tropical: max
        float4 r = make_float4(
            fmaxf(fmaxf(p0.x, p1.x), fmaxf(p2.x, p3.x)),
            fmaxf(fmaxf(p0.y, p1.y), fmaxf(p2.y, p3.y)),
            fmaxf(fmaxf(p0.z, p1.z), fmaxf(p2.z, p3.z)),
            fmaxf(fmaxf(p0.w, p1.w), fmaxf(p2.w, p3.w)));
        if (col < 512) {
            float4 b = *(const float4*)&qb[col];
            r.x += b.x; r.y += b.y; r.z += b.z; r.w += b.w;
            *(float4*)&Qo[(size_t)row * DM + col] = r;
        } else {
            float4 b = *(const float4*)&kb[col - 512];
            r.x += b.x; r.y += b.y; r.z += b.z; r.w += b.w;
            *(float4*)&Ko[(size_t)row * DM + col - 512] = r;
        }
    } else {           // V: add
        float4 b = *(const float4*)&vb[col - 1024];
        float4 r = make_float4(p0.x + p1.x + p2.x + p3.x + b.x,
                               p0.y + p1.y + p2.y + p3.y + b.y,
                               p0.z + p1.z + p2.z + p3.z + b.z,
                               p0.w + p1.w + p2.w + p3.w + b.w);
        *(float4*)&Vo[(size_t)row * DM + col - 1024] = r;
    }
}

// ---------------------------------------------------------------------------
// Kernel B: attention. Block = (q-tile 16, bh), 512 threads (8 waves).
// Scores: ty=tid>>5 q-row, tx=tid&31 owns kcols {2tx,2tx+1}; K staged
// k-major Kd[d][kcol]. Softmax in 32-lane shfl groups. PV: split-k over
// thread halves (kh=tid>>8), both V tiles staged per round, LDS combine.
// ---------------------------------------------------------------------------
__global__ __launch_bounds__(512) void attn_kernel(
    const float* __restrict__ Q, const float* __restrict__ K,
    const float* __restrict__ V, const float* __restrict__ g,
    const float* __restrict__ temp,
    float* __restrict__ attn_out, float* __restrict__ hout)
{
    const int tid = threadIdx.x;
    const int bh  = blockIdx.y;
    const int b   = bh >> 3, h = bh & 7;
    const int q0  = blockIdx.x * 16;
    const int ty  = tid >> 5;        // 0..15 q-row
    const int tx  = tid & 31;        // 0..31

    __shared__ float Qs[16][68];
    __shared__ float Kd[64][68];     // k-major K tile; reused as PV combine buf
    __shared__ float Vs[2][64][68];  // two V tiles for split-k PV
    __shared__ float Ss[16][260];

    if (tid < 256) {  // stage Q tile
        const int r = tid >> 4, c = (tid & 15) * 4;
        *(float4*)&Qs[r][c] =
            *(const float4*)&Q[(size_t)(b * LSEQ + q0 + r) * DM + h * DK + c];
    }
    const float gq   = g[(b * LSEQ + q0 + ty) * NH + h];
    const float invt = SCALEF / temp[h];

    const int sr = tid & 63;   // staging row
    const int sq = tid >> 6;   // 0..7 -> 8-float window

    // ---- scores ----
    for (int kt = 0; kt < 4; ++kt) {
        __syncthreads();
        {   // stage K transposed: Kd[d][kcol]
            const float* kp = K + (size_t)(b * LSEQ + kt * 64 + sr) * DM
                              + h * DK + sq * 8;
            #pragma unroll
            for (int i = 0; i < 2; ++i) {
                float4 v = *(const float4*)(kp + i * 4);
                const int d = sq * 8 + i * 4;
                Kd[d + 0][sr] = v.x;  Kd[d + 1][sr] = v.y;
                Kd[d + 2][sr] = v.z;  Kd[d + 3][sr] = v.w;
            }
        }
        __syncthreads();
        float d0 = 0.f, d1 = 0.f;
        float t0 = -INFINITY, t1 = -INFINITY;
        #pragma unroll
        for (int k4 = 0; k4 < 16; ++k4) {
            const float4 q4 = *(const float4*)&Qs[ty][k4 * 4];
            float2 ka = *(const float2*)&Kd[k4 * 4 + 0][tx * 2];
            float2 kb = *(const float2*)&Kd[k4 * 4 + 1][tx * 2];
            float2 kc = *(const float2*)&Kd[k4 * 4 + 2][tx * 2];
            float2 kd = *(const float2*)&Kd[k4 * 4 + 3][tx * 2];
            d0 = fmaf(q4.x, ka.x, d0); d0 = fmaf(q4.y, kb.x, d0);
            d0 = fmaf(q4.z, kc.x, d0); d0 = fmaf(q4.w, kd.x, d0);
            d1 = fmaf(q4.x, ka.y, d1); d1 = fmaf(q4.y, kb.y, d1);
            d1 = fmaf(q4.z, kc.y, d1); d1 = fmaf(q4.w, kd.y, d1);
            t0 = fmaxf(fmaxf(t0, q4.x + ka.x), q4.y + kb.x);
            t0 = fmaxf(fmaxf(t0, q4.z + kc.x), q4.w + kd.x);
            t1 = fmaxf(fmaxf(t1, q4.x + ka.y), q4.y + kb.y);
            t1 = fmaxf(fmaxf(t1, q4.z + kc.y), q4.w + kd.y);
        }
        const float gi = 1.f - gq;
        *(float2*)&Ss[ty][kt * 64 + tx * 2] = make_float2(
            (gq * t0 + gi * d0) * invt, (gq * t1 + gi * d1) * invt);
    }
    __syncthreads();

    // ---- softmax: row ty, 32 lanes x 8 elems ----
    {
        float m = -INFINITY;
        #pragma unroll
        for (int j = 0; j < 8; ++j) m = fmaxf(m, Ss[ty][tx + 32 * j]);
        #pragma unroll
        for (int o = 16; o; o >>= 1) m = fmaxf(m, __shfl_xor(m, o));
        float s = 0.f;
        #pragma unroll
        for (int j = 0; j < 8; ++j) {
            const float e = __expf(Ss[ty][tx + 32 * j] - m);
            Ss[ty][tx + 32 * j] = e;
            s += e;
        }
        #pragma unroll
        for (int o = 16; o; o >>= 1) s += __shfl_xor(s, o);
        const float rs = 1.f / s;
        #pragma unroll
        for (int j = 0; j < 8; ++j) Ss[ty][tx + 32 * j] *= rs;
    }
    __syncthreads();

    // ---- write attn tile ----
    {
        float* dst = attn_out + (size_t)(bh * LSEQ + q0) * LSEQ;
        #pragma unroll
        for (int i = 0; i < 2; ++i) {
            const int f   = i * 2048 + tid * 4;
            const int row = f >> 8, col = f & 255;
            *(float4*)&dst[f] = *(const float4*)&Ss[row][col];
        }
    }

    // ---- PV: kh = tid>>8 handles kt {2kh, 2kh+1}; thread owns (r, 4 d) ----
    const int kh = tid >> 8;          // 0/1
    const int bb = tid & 255;
    const int r  = bb >> 4;           // q-row
    const int d4 = bb & 15;           // d-col group
    float o0 = 0.f, o1 = 0.f, o2 = 0.f, o3 = 0.f;

    const int vr    = tid & 63;       // V row staged by this thread
    const int vslot = tid >> 6;       // 0..7: tile = vslot>>2, win = vslot&3

    for (int p = 0; p < 2; ++p) {
        __syncthreads();
        {   // stage both V tiles: Vs[0] <- kt=p, Vs[1] <- kt=2+p
            const int tile = vslot >> 2;
            const int tidx = tile ? (2 + p) : p;
            const float* vp = V + (size_t)(b * LSEQ + tidx * 64 + vr) * DM
                              + h * DK + (vslot & 3) * 16;
            #pragma unroll
            for (int i = 0; i < 4; ++i)
                *(float4*)&Vs[tile][vr][(vslot & 3) * 16 + i * 4] =
                    *(const float4*)(vp + i * 4);
        }
        __syncthreads();
        const int kt = kh * 2 + p;
        #pragma unroll 4
        for (int k4 = 0; k4 < 16; ++k4) {
            float4 a  = *(const float4*)&Ss[r][kt * 64 + k4 * 4];
            float4 v0 = *(const float4*)&Vs[kh][k4 * 4 + 0][d4 * 4];
            float4 v1 = *(const float4*)&Vs[kh][k4 * 4 + 1][d4 * 4];
            float4 v2 = *(const float4*)&Vs[kh][k4 * 4 + 2][d4 * 4];
            float4 v3 = *(const float4*)&Vs[kh][k4 * 4 + 3][d4 * 4];
            o0 = fmaf(a.x, v0.x, o0); o0 = fmaf(a.y, v1.x, o0);
            o0 = fmaf(a.z, v2.x, o0); o0 = fmaf(a.w, v3.x, o0);
            o1 = fmaf(a.x, v0.y, o1); o1 = fmaf(a.y, v1.y, o1);
            o1 = fmaf(a.z, v2.y, o1); o1 = fmaf(a.w, v3.y, o1);
            o2 = fmaf(a.x, v0.z, o2); o2 = fmaf(a.y, v1.z, o2);
            o2 = fmaf(a.z, v2.z, o2); o2 = fmaf(a.w, v3.z, o2);
            o3 = fmaf(a.x, v0.w, o3); o3 = fmaf(a.y, v1.w, o3);
            o3 = fmaf(a.z, v2.w, o3); o3 = fmaf(a.w, v3.w, o3);
        }
    }
    __syncthreads();
    if (kh == 1)   // publish partials in Kd (dead after score phase)
        *(float4*)&Kd[r][d4 * 4] = make_float4(o0, o1, o2, o3);
    __syncthreads();
    if (kh == 0) {
        float4 po = *(const float4*)&Kd[r][d4 * 4];
        *(float4*)&hout[(size_t)(b * LSEQ + q0 + r) * DM + h * DK + d4 * 4] =
            make_float4(o0 + po.x, o1 + po.y, o2 + po.z, o3 + po.w);
    }
}

// ---------------------------------------------------------------------------
// Kernel C: oproj partial, split-k=8. bx: ks = bx&7, t = bx>>3 (8x8 tiles).
// 64x64 tile, 4x4/thread, single 64-k chunk. Writes P2[ks][512][512].
// ---------------------------------------------------------------------------
__global__ __launch_bounds__(256) void oproj_kernel(
    const float* __restrict__ hout,
    const float* __restrict__ oW,
    float* __restrict__ P2)
{
    const int tid = threadIdx.x;
    const int bx  = blockIdx.x;
    const int ks  = bx & 7;
    const int t   = bx >> 3;
    const int row0 = (t >> 3) * 64;
    const int col0 = (t & 7) * 64;
    const int kbase = ks * 64;

    __shared__ float Xs[KC][68];
    __shared__ float Ws[KC][68];

    const int ty = tid >> 4, tx = tid & 15;
    const int sr = tid & 63;
    const int sq = tid >> 6;

    {
        const float* xp = hout + (size_t)(row0 + sr) * DM + kbase + sq * 16;
        const float* wp = oW   + (size_t)(col0 + sr) * DM + kbase + sq * 16;
        #pragma unroll
        for (int i = 0; i < 4; ++i) {
            float4 xv = *(const float4*)(xp + i * 4);
            float4 wv = *(const float4*)(wp + i * 4);
            const int kk = sq * 16 + i * 4;
            Xs[kk + 0][sr] = xv.x;  Xs[kk + 1][sr] = xv.y;
            Xs[kk + 2][sr] = xv.z;  Xs[kk + 3][sr] = xv.w;
            Ws[kk + 0][sr] = wv.x;  Ws[kk + 1][sr] = wv.y;
            Ws[kk + 2][sr] = wv.z;  Ws[kk + 3][sr] = wv.w;
        }
    }
    __syncthreads();

    float acc[4][4] = {};
    #pragma unroll 4
    for (int kp = 0; kp < KC / 2; ++kp) {
        const int kk = kp * 2;
        float4 x0 = *(const float4*)&Xs[kk    ][ty * 4];
        float4 x1 = *(const float4*)&Xs[kk + 1][ty * 4];
        float4 w0 = *(const float4*)&Ws[kk    ][tx * 4];
        float4 w1 = *(const float4*)&Ws[kk + 1][tx * 4];
        const float xa0[4] = {x0.x, x0.y, x0.z, x0.w};
        const float xa1[4] = {x1.x, x1.y, x1.z, x1.w};
        const float wa0[4] = {w0.x, w0.y, w0.z, w0.w};
        const float wa1[4] = {w1.x, w1.y, w1.z, w1.w};
        #pragma unroll
        for (int i = 0; i < 4; ++i)
            #pragma unroll
            for (int j = 0; j < 4; ++j) {
                acc[i][j] = fmaf(xa0[i], wa0[j], acc[i][j]);
                acc[i][j] = fmaf(xa1[i], wa1[j], acc[i][j]);
            }
    }

    #pragma unroll
    for (int i = 0; i < 4; ++i) {
        const int r = row0 + ty * 4 + i;
        *(float4*)&P2[((size_t)ks * 512 + r) * 512 + col0 + tx * 4] =
            make_float4(acc[i][0], acc[i][1], acc[i][2], acc[i][3]);
    }
}

// ---------------------------------------------------------------------------
// Reduce 2: fold 8 oproj partials + ob -> out. 256 blocks x 256 thr.
// ---------------------------------------------------------------------------
__global__ __launch_bounds__(256) void oproj_reduce_kernel(
    const float* __restrict__ P2, const float* __restrict__ ob,
    float* __restrict__ out)
{
    const int e   = blockIdx.x * 256 + threadIdx.x;  // float4 index
    const int row = e >> 7;
    const int col = (e & 127) * 4;
    const size_t base = (size_t)row * 512 + col;

    float4 b = *(const float4*)&ob[col];
    float4 r = b;
    #pragma unroll
    for (int s = 0; s < 8; ++s) {
        float4 p = *(const float4*)&P2[base + (size_t)s * 262144];
        r.x += p.x; r.y += p.y; r.z += p.z; r.w += p.w;
    }
    *(float4*)&out[base] = r;
}

extern "C" void kernel_launch(void* const* d_in, const int* in_sizes, int n_in,
                              void* d_out, int out_size, void* d_ws, size_t ws_size,
                              hipStream_t stream)
{
    const float* x    = (const float*)d_in[0];
    const float* qW   = (const float*)d_in[1];
    const float* qb   = (const float*)d_in[2];
    const float* kW   = (const float*)d_in[3];
    const float* kb   = (const float*)d_in[4];
    const float* vW   = (const float*)d_in[5];
    const float* vb   = (const float*)d_in[6];
    const float* oW   = (const float*)d_in[7];
    const float* ob   = (const float*)d_in[8];
    const float* gW   = (const float*)d_in[9];
    const float* gb   = (const float*)d_in[10];
    const float* temp = (const float*)d_in[11];

    float* out      = (float*)d_out;                 // (B,L,512)
    float* attn_out = out + NB * LSEQ * DM;          // (B,H,L,L)

    float* ws   = (float*)d_ws;
    float* Qo   = ws;                                // 262144 floats
    float* Ko   = Qo + NB * LSEQ * DM;               // 262144
    float* Vo   = Ko + NB * LSEQ * DM;               // 262144
    float* go   = Vo + NB * LSEQ * DM;               // 4096
    float* hout = go + NB * LSEQ * NH;               // 262144 (merged B,L,512)
    float* P1   = hout + NB * LSEQ * DM;             // 4*512*1536 = 3145728
    float* P2   = P1;                                // aliases P1 (dead by then)

    qkvg_kernel<<<dim3(784), 256, 0, stream>>>(
        x, qW, kW, vW, gW, gb, P1, go);
    qkv_reduce_kernel<<<dim3(768), 256, 0, stream>>>(
        P1, qb, kb, vb, Qo, Ko, Vo);
    attn_kernel<<<dim3(16, 16), 512, 0, stream>>>(
        Qo, Ko, Vo, go, temp, attn_out, hout);
    oproj_kernel<<<dim3(512), 256, 0, stream>>>(
        hout, oW, P2);
    oproj_reduce_kernel<<<dim3(256), 256, 0, stream>>>(
        P2, ob, out);
}